// Round 10
// baseline (129.309 us; speedup 1.0000x reference)
//
#include <hip/hip_runtime.h>

#define HW  16384
#define WD  128

#define TS   16            // center tile side
#define HS   18            // halo side
#define HP   (HS * HS)     // 324 halo pixels
#define PRS  20            // padded halo row stride (slots)
#define PLS  360           // plane stride per c8 (uint4 slots) = 18*20

__device__ __forceinline__ unsigned short f2bf(float f) {
    unsigned int u = __builtin_bit_cast(unsigned int, f);
    u += 0x7FFFu + ((u >> 16) & 1u);          // RNE
    return (unsigned short)(u >> 16);
}
__device__ __forceinline__ float bf2f(unsigned int s) {
    return __builtin_bit_cast(float, (s & 0xFFFFu) << 16);
}
__device__ __forceinline__ float ftanh(float v) {
    const float e = __expf(2.0f * v);
    return 1.0f - __fdividef(2.0f, e + 1.0f);
}

// ---- la_t: t = tanh(bn1(conv1(x))) channel-split 2x, PLUS bf16 x repack.
//   TASK-MAJOR grid: blockIdx.x = z = h*8 + p  ->  linear id % 8 == p.
//   All blocks producing group-p planes land on XCD p — the same XCD that
//   la_fused's id%8==g pins the consumer to. xbf dirty set per XCD ~2MB
//   (fits 4MB L2) -> consumer reads become L2 hits. Also h=0/h=1 siblings
//   (same p) share an XCD, so the 2nd x-slab read is L2-served.
//   Plain launch_bounds: R4's (256,8) forced VGPR=32 and spilled xv[32]
//   to scratch — never bound min-waves here.
__global__ __launch_bounds__(256) void la_t(
    const float* __restrict__ x,
    const float* __restrict__ w1, const float* __restrict__ b1,
    const float* __restrict__ g1, const float* __restrict__ be1,
    const float* __restrict__ m1, const float* __restrict__ v1,
    ushort4* __restrict__ t4, uint4* __restrict__ xbf)
{
    const int z   = blockIdx.x;                              // 0..15 task
    const int b   = blockIdx.y;
    const int pix = blockIdx.z * blockDim.x + threadIdx.x;   // 0..16383
    const int p   = z & 7;                                   // t-group
    const int h   = z >> 3;                                  // output half

    const float* xp = x + (size_t)(b * 256 + p * 32) * HW + pix;
    float xv[32];
#pragma unroll
    for (int c = 0; c < 32; ++c) xv[c] = xp[(size_t)c * HW];

    // bf16 repack of this half's 16 channels -> 2 dense uint4 planes
#pragma unroll
    for (int j = 0; j < 2; ++j) {
        const int c8 = h * 2 + j;                 // uint4 plane, 8 channels
        uint4 u;
        u.x = (unsigned)f2bf(xv[c8 * 8 + 0]) | ((unsigned)f2bf(xv[c8 * 8 + 1]) << 16);
        u.y = (unsigned)f2bf(xv[c8 * 8 + 2]) | ((unsigned)f2bf(xv[c8 * 8 + 3]) << 16);
        u.z = (unsigned)f2bf(xv[c8 * 8 + 4]) | ((unsigned)f2bf(xv[c8 * 8 + 5]) << 16);
        u.w = (unsigned)f2bf(xv[c8 * 8 + 6]) | ((unsigned)f2bf(xv[c8 * 8 + 7]) << 16);
        xbf[((size_t)((b * 8 + p) * 4 + c8)) * HW + pix] = u;
    }

    const float* w1g = w1 + p * 256 + h * 4 * 32;
    float tv[4];
#pragma unroll
    for (int o = 0; o < 4; ++o) {
        float a = 0.f;
#pragma unroll
        for (int ci = 0; ci < 32; ++ci) a = fmaf(xv[ci], w1g[o * 32 + ci], a);
        const int ch = p * 8 + h * 4 + o;
        const float inv = g1[ch] * rsqrtf(v1[ch] + 1e-5f);
        const float add = be1[ch] + (b1[ch] - m1[ch]) * inv;
        tv[o] = ftanh(fmaf(a, inv, add));
    }

    t4[((size_t)((b * 8 + p) * 2 + h)) * HW + pix] =
        make_ushort4(f2bf(tv[0]), f2bf(tv[1]), f2bf(tv[2]), f2bf(tv[3]));
}

// ---- la_fused: bf16 x-tile copy (4 uint4 loads/px) + in-block nb +
//      mask conv + softmax + taps + Wv. One block per (b,g,tile) — R8's
//      output split duplicated the stage (the expensive part) and lost.
// grid = (16 bg, 64 tiles): linear id % 8 == g -> per-XCD xbf locality
// (xbf for g produced on XCD g by la_t's task-major grid).
__global__ __launch_bounds__(256, 4) void la_fused(
    const float* __restrict__ w2, const float* __restrict__ b2,
    const float* __restrict__ g2, const float* __restrict__ be2,
    const float* __restrict__ m2, const float* __restrict__ v2,
    const float* __restrict__ wv,
    const ushort4* __restrict__ t4, const uint4* __restrict__ xbf,
    float* __restrict__ out)
{
    __shared__ uint4 xt[4 * PLS];              // x tile, bf16x8: 23040 B
    __shared__ float nbs[PLS];                 // neighbor plane fp32: 1440 B

    const int tid  = threadIdx.x;
    const int bg   = blockIdx.x;
    const int tile = blockIdx.y;               // 0..63
    const int b    = bg >> 3, g = bg & 7;
    const int ty0  = (tile >> 3) * TS;
    const int tx0  = (tile & 7) * TS;

    const uint4*   xg = xbf + (size_t)((b * 8 + g) * 4) * HW;
    const ushort4* t0 = t4  + (size_t)(b * 16) * HW;      // group-0 planes

    // ---- T14 prefetch: center tA/tB loads are LDS-independent — issue
    // them BEFORE the stage loop so their latency hides under staging.
    const int cy  = tid >> 4, cx = tid & 15;
    const int ciy = ty0 + cy, cix = tx0 + cx;
    const int cpx = ciy * WD + cix;

    const int mc0    = 8 + 9 * g;
    const int pa     = mc0 / 10;               // == g
    const int pb     = (mc0 + 8) / 10;         // == min(g+1, 7)
    const int ksplit = 10 - (mc0 - pa * 10);

    const ushort4 tAlo = t4[((size_t)((b * 8 + pa) * 2 + 0)) * HW + cpx];
    const ushort4 tAhi = t4[((size_t)((b * 8 + pa) * 2 + 1)) * HW + cpx];
    const ushort4 tBlo = t4[((size_t)((b * 8 + pb) * 2 + 0)) * HW + cpx];
    const ushort4 tBhi = t4[((size_t)((b * 8 + pb) * 2 + 1)) * HW + cpx];

    // bn2 constants for neighbor channel g (conv2 group 0, out row g)
    const float inv2n = g2[g] * rsqrtf(v2[g] + 1e-5f);
    const float add2n = be2[g] + (b2[g] - m2[g]) * inv2n;

    // ---- phase 1: halo -> LDS (pure bf16 copy) + nb plane from t0 ----
    for (int hp = tid; hp < HP; hp += 256) {
        const int hy = hp / HS, hx = hp - hy * HS;
        const int iy = ty0 + hy - 1, ix = tx0 + hx - 1;
        const int slot = hy * PRS + hx;
        if (((unsigned)iy < 128u) && ((unsigned)ix < 128u)) {
            const int po = iy * WD + ix;
            // nb = bn2(conv2 row g of group 0, applied to bf16 t0)
            const ushort4 ta = t0[po];
            const ushort4 tb = t0[(size_t)HW + po];
            float an = 0.f;
            an = fmaf(bf2f(ta.x), w2[g * 8 + 0], an);
            an = fmaf(bf2f(ta.y), w2[g * 8 + 1], an);
            an = fmaf(bf2f(ta.z), w2[g * 8 + 2], an);
            an = fmaf(bf2f(ta.w), w2[g * 8 + 3], an);
            an = fmaf(bf2f(tb.x), w2[g * 8 + 4], an);
            an = fmaf(bf2f(tb.y), w2[g * 8 + 5], an);
            an = fmaf(bf2f(tb.z), w2[g * 8 + 6], an);
            an = fmaf(bf2f(tb.w), w2[g * 8 + 7], an);
            nbs[slot] = fmaf(an, inv2n, add2n);
#pragma unroll
            for (int c8 = 0; c8 < 4; ++c8)
                xt[c8 * PLS + slot] = xg[(size_t)c8 * HW + po];
        } else {
            const uint4 z = make_uint4(0u, 0u, 0u, 0u);
#pragma unroll
            for (int c8 = 0; c8 < 4; ++c8) xt[c8 * PLS + slot] = z;
            nbs[slot] = 0.f;       // zero-padded neighbor
        }
    }
    __syncthreads();

    // ---- phase 2: one center pixel per thread ----
    float tA[8], tB[8];
    tA[0] = bf2f(tAlo.x); tA[1] = bf2f(tAlo.y);
    tA[2] = bf2f(tAlo.z); tA[3] = bf2f(tAlo.w);
    tA[4] = bf2f(tAhi.x); tA[5] = bf2f(tAhi.y);
    tA[6] = bf2f(tAhi.z); tA[7] = bf2f(tAhi.w);
    tB[0] = bf2f(tBlo.x); tB[1] = bf2f(tBlo.y);
    tB[2] = bf2f(tBlo.z); tB[3] = bf2f(tBlo.w);
    tB[4] = bf2f(tBhi.x); tB[5] = bf2f(tBhi.y);
    tB[6] = bf2f(tBhi.z); tB[7] = bf2f(tBhi.w);

    float lg[9];
    float mx = -1e30f;
#pragma unroll
    for (int k = 0; k < 9; ++k) {
        const int mc = mc0 + k;
        const int p  = (k < ksplit) ? pa : pb;
        const int o  = mc - p * 10;
        const float* w2p = w2 + p * 80 + o * 8;
        float a = 0.f;
#pragma unroll
        for (int i = 0; i < 8; ++i) {
            const float ti = (k < ksplit) ? tA[i] : tB[i];
            a = fmaf(ti, w2p[i], a);
        }
        const float inv = g2[mc] * rsqrtf(v2[mc] + 1e-5f);
        const float add = be2[mc] + (b2[mc] - m2[mc]) * inv;
        lg[k] = fmaf(a, inv, add) + nbs[(cy + k / 3) * PRS + (cx + k % 3)];
        mx = fmaxf(mx, lg[k]);
    }
    float ssum = 0.f;
#pragma unroll
    for (int k = 0; k < 9; ++k) { lg[k] = __expf(lg[k] - mx); ssum += lg[k]; }
    const float rs = 1.f / ssum;               // applied once at the store

    // s = sum_k e_k * x_tap  (OOB taps read x==0 from LDS)
    float s[32];
#pragma unroll
    for (int c = 0; c < 32; ++c) s[c] = 0.f;
#pragma unroll
    for (int k = 0; k < 9; ++k) {
        const int slot = (cy + k / 3) * PRS + (cx + k % 3);
        const float e = lg[k];
#pragma unroll
        for (int c8 = 0; c8 < 4; ++c8) {
            const uint4 u = xt[c8 * PLS + slot];
            s[c8 * 8 + 0] = fmaf(e, bf2f(u.x),       s[c8 * 8 + 0]);
            s[c8 * 8 + 1] = fmaf(e, bf2f(u.x >> 16), s[c8 * 8 + 1]);
            s[c8 * 8 + 2] = fmaf(e, bf2f(u.y),       s[c8 * 8 + 2]);
            s[c8 * 8 + 3] = fmaf(e, bf2f(u.y >> 16), s[c8 * 8 + 3]);
            s[c8 * 8 + 4] = fmaf(e, bf2f(u.z),       s[c8 * 8 + 4]);
            s[c8 * 8 + 5] = fmaf(e, bf2f(u.z >> 16), s[c8 * 8 + 5]);
            s[c8 * 8 + 6] = fmaf(e, bf2f(u.w),       s[c8 * 8 + 6]);
            s[c8 * 8 + 7] = fmaf(e, bf2f(u.w >> 16), s[c8 * 8 + 7]);
        }
    }

    // out = rs * (Wv . s)
    const float* wvg = wv + g * 1024;
    float* og = out + (size_t)(b * 256 + g * 32) * HW + cpx;
#pragma unroll 4
    for (int o = 0; o < 32; ++o) {
        const float* wp = wvg + o * 32;
        float a = 0.f;
#pragma unroll
        for (int ci = 0; ci < 32; ++ci) a = fmaf(s[ci], wp[ci], a);
        __builtin_nontemporal_store(a * rs, og + (size_t)o * HW);
    }
}

extern "C" void kernel_launch(void* const* d_in, const int* in_sizes, int n_in,
                              void* d_out, int out_size, void* d_ws, size_t ws_size,
                              hipStream_t stream)
{
    const float* x   = (const float*)d_in[0];
    const float* w1  = (const float*)d_in[1];
    const float* b1  = (const float*)d_in[2];
    const float* g1  = (const float*)d_in[3];
    const float* be1 = (const float*)d_in[4];
    const float* m1  = (const float*)d_in[5];
    const float* v1  = (const float*)d_in[6];
    const float* w2  = (const float*)d_in[7];
    const float* b2  = (const float*)d_in[8];
    const float* g2  = (const float*)d_in[9];
    const float* be2 = (const float*)d_in[10];
    const float* m2  = (const float*)d_in[11];
    const float* v2  = (const float*)d_in[12];
    const float* wv  = (const float*)d_in[13];

    float* out = (float*)d_out;
    // workspace: t4 (32 planes x 8B = 4.2 MB) | xbf (64 uint4 planes x 16B = 16.8 MB)
    ushort4* t4  = (ushort4*)d_ws;
    uint4*   xbf = (uint4*)((char*)d_ws + (size_t)32 * HW * 8);

    dim3 blk(256);
    dim3 gt(16, 2, HW / 256);      // TASK-MAJOR: id%8 == p -> XCD-local xbf
    dim3 gfd(16, 64);              // (bg, tile): id%8 == g -> XCD locality

    hipLaunchKernelGGL(la_t, gt, blk, 0, stream,
                       x, w1, b1, g1, be1, m1, v1, t4, xbf);
    hipLaunchKernelGGL(la_fused, gfd, blk, 0, stream,
                       w2, b2, g2, be2, m2, v2, wv, t4, xbf, out);
}

// Round 11
// 124.295 us; speedup vs baseline: 1.0403x; 1.0403x over previous
//
#include <hip/hip_runtime.h>

#define HW  16384
#define WD  128

#define TS   16            // center tile side
#define HS   18            // halo side
#define HP   (HS * HS)     // 324 halo pixels
#define PRS  20            // padded halo row stride (slots)
#define PLS  360           // plane stride per c8 (uint4 slots) = 18*20
#define SROW 80            // S-matrix LDS row stride in bytes (2-way banks)

typedef __attribute__((ext_vector_type(8))) short bf16x8;
typedef __attribute__((ext_vector_type(4))) float f32x4;

__device__ __forceinline__ unsigned short f2bf(float f) {
    unsigned int u = __builtin_bit_cast(unsigned int, f);
    u += 0x7FFFu + ((u >> 16) & 1u);          // RNE
    return (unsigned short)(u >> 16);
}
__device__ __forceinline__ float bf2f(unsigned int s) {
    return __builtin_bit_cast(float, (s & 0xFFFFu) << 16);
}
__device__ __forceinline__ float ftanh(float v) {
    const float e = __expf(2.0f * v);
    return 1.0f - __fdividef(2.0f, e + 1.0f);
}

// ---- la_t: unchanged from R10 (task-major grid, channel-split 2x) ---------
__global__ __launch_bounds__(256) void la_t(
    const float* __restrict__ x,
    const float* __restrict__ w1, const float* __restrict__ b1,
    const float* __restrict__ g1, const float* __restrict__ be1,
    const float* __restrict__ m1, const float* __restrict__ v1,
    ushort4* __restrict__ t4, uint4* __restrict__ xbf)
{
    const int z   = blockIdx.x;                              // 0..15 task
    const int b   = blockIdx.y;
    const int pix = blockIdx.z * blockDim.x + threadIdx.x;   // 0..16383
    const int p   = z & 7;                                   // t-group
    const int h   = z >> 3;                                  // output half

    const float* xp = x + (size_t)(b * 256 + p * 32) * HW + pix;
    float xv[32];
#pragma unroll
    for (int c = 0; c < 32; ++c) xv[c] = xp[(size_t)c * HW];

#pragma unroll
    for (int j = 0; j < 2; ++j) {
        const int c8 = h * 2 + j;                 // uint4 plane, 8 channels
        uint4 u;
        u.x = (unsigned)f2bf(xv[c8 * 8 + 0]) | ((unsigned)f2bf(xv[c8 * 8 + 1]) << 16);
        u.y = (unsigned)f2bf(xv[c8 * 8 + 2]) | ((unsigned)f2bf(xv[c8 * 8 + 3]) << 16);
        u.z = (unsigned)f2bf(xv[c8 * 8 + 4]) | ((unsigned)f2bf(xv[c8 * 8 + 5]) << 16);
        u.w = (unsigned)f2bf(xv[c8 * 8 + 6]) | ((unsigned)f2bf(xv[c8 * 8 + 7]) << 16);
        xbf[((size_t)((b * 8 + p) * 4 + c8)) * HW + pix] = u;
    }

    const float* w1g = w1 + p * 256 + h * 4 * 32;
    float tv[4];
#pragma unroll
    for (int o = 0; o < 4; ++o) {
        float a = 0.f;
#pragma unroll
        for (int ci = 0; ci < 32; ++ci) a = fmaf(xv[ci], w1g[o * 32 + ci], a);
        const int ch = p * 8 + h * 4 + o;
        const float inv = g1[ch] * rsqrtf(v1[ch] + 1e-5f);
        const float add = be1[ch] + (b1[ch] - m1[ch]) * inv;
        tv[o] = ftanh(fmaf(a, inv, add));
    }

    t4[((size_t)((b * 8 + p) * 2 + h)) * HW + pix] =
        make_ushort4(f2bf(tv[0]), f2bf(tv[1]), f2bf(tv[2]), f2bf(tv[3]));
}

// ---- la_fused: stage + nb + softmax + taps as before; Wv epilogue is now
//      a per-block 256x32x32 GEMM on the matrix cores:
//        S[px][ci] = rs*s  (bf16, LDS, reusing dead xt region, 80B rows)
//        C = S . Wv^T  via 8x mfma_f32_16x16x32_bf16 per wave
//      replacing 1024 scalar FMA + 32 scalar stores per thread.
__global__ __launch_bounds__(256) void la_fused(
    const float* __restrict__ w2, const float* __restrict__ b2,
    const float* __restrict__ g2, const float* __restrict__ be2,
    const float* __restrict__ m2, const float* __restrict__ v2,
    const float* __restrict__ wv,
    const ushort4* __restrict__ t4, const uint4* __restrict__ xbf,
    float* __restrict__ out)
{
    __shared__ uint4 xt[4 * PLS];              // x tile bf16x8 / S matrix alias
    __shared__ float nbs[PLS];                 // neighbor plane fp32: 1440 B

    const int tid  = threadIdx.x;
    const int bg   = blockIdx.x;
    const int tile = blockIdx.y;               // 0..63
    const int b    = bg >> 3, g = bg & 7;
    const int ty0  = (tile >> 3) * TS;
    const int tx0  = (tile & 7) * TS;
    const int lane = tid & 63, wv4 = tid >> 6; // lane, wave id

    const uint4*   xg = xbf + (size_t)((b * 8 + g) * 4) * HW;
    const ushort4* t0 = t4  + (size_t)(b * 16) * HW;      // group-0 planes

    // ---- B fragments for the Wv GEMM (uniform; issued early, hides under
    // staging). B[k=ci][n=o]: lane holds col o=16nt+(lane&15),
    // k = 8*(lane>>4)+j  ->  wvg[o*32 + 8*(lane>>4) + j], 8 consecutive fp32.
    const float* wvg = wv + g * 1024;
    bf16x8 bfrag[2];
#pragma unroll
    for (int nt = 0; nt < 2; ++nt) {
        const float* wp = wvg + (nt * 16 + (lane & 15)) * 32 + (lane >> 4) * 8;
        bf16x8 f;
#pragma unroll
        for (int j = 0; j < 8; ++j) f[j] = (short)f2bf(wp[j]);
        bfrag[nt] = f;
    }

    // ---- T14 prefetch: center tA/tB loads (LDS-independent)
    const int cy  = tid >> 4, cx = tid & 15;
    const int cpx = (ty0 + cy) * WD + (tx0 + cx);

    const int mc0    = 8 + 9 * g;
    const int pa     = mc0 / 10;               // == g
    const int pb     = (mc0 + 8) / 10;         // == min(g+1, 7)
    const int ksplit = 10 - (mc0 - pa * 10);

    const ushort4 tAlo = t4[((size_t)((b * 8 + pa) * 2 + 0)) * HW + cpx];
    const ushort4 tAhi = t4[((size_t)((b * 8 + pa) * 2 + 1)) * HW + cpx];
    const ushort4 tBlo = t4[((size_t)((b * 8 + pb) * 2 + 0)) * HW + cpx];
    const ushort4 tBhi = t4[((size_t)((b * 8 + pb) * 2 + 1)) * HW + cpx];

    const float inv2n = g2[g] * rsqrtf(v2[g] + 1e-5f);
    const float add2n = be2[g] + (b2[g] - m2[g]) * inv2n;

    // ---- phase 1: halo -> LDS (pure bf16 copy) + nb plane from t0 ----
    for (int hp = tid; hp < HP; hp += 256) {
        const int hy = hp / HS, hx = hp - hy * HS;
        const int iy = ty0 + hy - 1, ix = tx0 + hx - 1;
        const int slot = hy * PRS + hx;
        if (((unsigned)iy < 128u) && ((unsigned)ix < 128u)) {
            const int po = iy * WD + ix;
            const ushort4 ta = t0[po];
            const ushort4 tb = t0[(size_t)HW + po];
            float an = 0.f;
            an = fmaf(bf2f(ta.x), w2[g * 8 + 0], an);
            an = fmaf(bf2f(ta.y), w2[g * 8 + 1], an);
            an = fmaf(bf2f(ta.z), w2[g * 8 + 2], an);
            an = fmaf(bf2f(ta.w), w2[g * 8 + 3], an);
            an = fmaf(bf2f(tb.x), w2[g * 8 + 4], an);
            an = fmaf(bf2f(tb.y), w2[g * 8 + 5], an);
            an = fmaf(bf2f(tb.z), w2[g * 8 + 6], an);
            an = fmaf(bf2f(tb.w), w2[g * 8 + 7], an);
            nbs[slot] = fmaf(an, inv2n, add2n);
#pragma unroll
            for (int c8 = 0; c8 < 4; ++c8)
                xt[c8 * PLS + slot] = xg[(size_t)c8 * HW + po];
        } else {
            const uint4 z = make_uint4(0u, 0u, 0u, 0u);
#pragma unroll
            for (int c8 = 0; c8 < 4; ++c8) xt[c8 * PLS + slot] = z;
            nbs[slot] = 0.f;
        }
    }
    __syncthreads();

    // ---- phase 2: softmax + taps (one center pixel per thread) ----
    float tA[8], tB[8];
    tA[0] = bf2f(tAlo.x); tA[1] = bf2f(tAlo.y);
    tA[2] = bf2f(tAlo.z); tA[3] = bf2f(tAlo.w);
    tA[4] = bf2f(tAhi.x); tA[5] = bf2f(tAhi.y);
    tA[6] = bf2f(tAhi.z); tA[7] = bf2f(tAhi.w);
    tB[0] = bf2f(tBlo.x); tB[1] = bf2f(tBlo.y);
    tB[2] = bf2f(tBlo.z); tB[3] = bf2f(tBlo.w);
    tB[4] = bf2f(tBhi.x); tB[5] = bf2f(tBhi.y);
    tB[6] = bf2f(tBhi.z); tB[7] = bf2f(tBhi.w);

    float lg[9];
    float mx = -1e30f;
#pragma unroll
    for (int k = 0; k < 9; ++k) {
        const int mc = mc0 + k;
        const int p  = (k < ksplit) ? pa : pb;
        const int o  = mc - p * 10;
        const float* w2p = w2 + p * 80 + o * 8;
        float a = 0.f;
#pragma unroll
        for (int i = 0; i < 8; ++i) {
            const float ti = (k < ksplit) ? tA[i] : tB[i];
            a = fmaf(ti, w2p[i], a);
        }
        const float inv = g2[mc] * rsqrtf(v2[mc] + 1e-5f);
        const float add = be2[mc] + (b2[mc] - m2[mc]) * inv;
        lg[k] = fmaf(a, inv, add) + nbs[(cy + k / 3) * PRS + (cx + k % 3)];
        mx = fmaxf(mx, lg[k]);
    }
    float ssum = 0.f;
#pragma unroll
    for (int k = 0; k < 9; ++k) { lg[k] = __expf(lg[k] - mx); ssum += lg[k]; }
    const float rs = 1.f / ssum;

    float s[32];
#pragma unroll
    for (int c = 0; c < 32; ++c) s[c] = 0.f;
#pragma unroll
    for (int k = 0; k < 9; ++k) {
        const int slot = (cy + k / 3) * PRS + (cx + k % 3);
        const float e = lg[k];
#pragma unroll
        for (int c8 = 0; c8 < 4; ++c8) {
            const uint4 u = xt[c8 * PLS + slot];
            s[c8 * 8 + 0] = fmaf(e, bf2f(u.x),       s[c8 * 8 + 0]);
            s[c8 * 8 + 1] = fmaf(e, bf2f(u.x >> 16), s[c8 * 8 + 1]);
            s[c8 * 8 + 2] = fmaf(e, bf2f(u.y),       s[c8 * 8 + 2]);
            s[c8 * 8 + 3] = fmaf(e, bf2f(u.y >> 16), s[c8 * 8 + 3]);
            s[c8 * 8 + 4] = fmaf(e, bf2f(u.z),       s[c8 * 8 + 4]);
            s[c8 * 8 + 5] = fmaf(e, bf2f(u.z >> 16), s[c8 * 8 + 5]);
            s[c8 * 8 + 6] = fmaf(e, bf2f(u.w),       s[c8 * 8 + 6]);
            s[c8 * 8 + 7] = fmaf(e, bf2f(u.w >> 16), s[c8 * 8 + 7]);
        }
    }

    // ---- phase 3: Wv GEMM on matrix cores ----
    // S row px = tid: 32 bf16 of rs*s (rs folded here, exact per-pixel).
    __syncthreads();                           // all taps done reading xt
    char* Sb = (char*)xt;                      // reuse: 256 rows x SROW bytes
    {
        uint4* row = (uint4*)(Sb + tid * SROW);
#pragma unroll
        for (int q = 0; q < 4; ++q) {
            uint4 u;
            u.x = (unsigned)f2bf(rs * s[q * 8 + 0]) | ((unsigned)f2bf(rs * s[q * 8 + 1]) << 16);
            u.y = (unsigned)f2bf(rs * s[q * 8 + 2]) | ((unsigned)f2bf(rs * s[q * 8 + 3]) << 16);
            u.z = (unsigned)f2bf(rs * s[q * 8 + 4]) | ((unsigned)f2bf(rs * s[q * 8 + 5]) << 16);
            u.w = (unsigned)f2bf(rs * s[q * 8 + 6]) | ((unsigned)f2bf(rs * s[q * 8 + 7]) << 16);
            row[q] = u;
        }
    }
    __syncthreads();

    // wave wv4 computes S rows 64*wv4 .. +63: 4 M-tiles x 2 N-tiles, K=32.
    // A frag: lane holds row 16t+(lane&15), k = 8*(lane>>4)+j  (one b128).
    // C frag: col = lane&15 (+16*nt), rows 4*(lane>>4)+j  -> 4 contig px.
    float* outg = out + (size_t)(b * 256 + g * 32) * HW;
#pragma unroll
    for (int t = 0; t < 4; ++t) {
        const uint4 av = *(const uint4*)(Sb +
            (wv4 * 64 + t * 16 + (lane & 15)) * SROW + (lane >> 4) * 16);
        const bf16x8 af = __builtin_bit_cast(bf16x8, av);
#pragma unroll
        for (int nt = 0; nt < 2; ++nt) {
            f32x4 c = {0.f, 0.f, 0.f, 0.f};
            c = __builtin_amdgcn_mfma_f32_16x16x32_bf16(af, bfrag[nt], c, 0, 0, 0);
            const int ch  = nt * 16 + (lane & 15);
            const int idx = wv4 * 64 + t * 16 + 4 * (lane >> 4);  // px base
            const int oy  = ty0 + (idx >> 4), ox = tx0 + (idx & 15);
            f32x4* addr = (f32x4*)(outg + (size_t)ch * HW + oy * WD + ox);
            __builtin_nontemporal_store(c, addr);
        }
    }
}

extern "C" void kernel_launch(void* const* d_in, const int* in_sizes, int n_in,
                              void* d_out, int out_size, void* d_ws, size_t ws_size,
                              hipStream_t stream)
{
    const float* x   = (const float*)d_in[0];
    const float* w1  = (const float*)d_in[1];
    const float* b1  = (const float*)d_in[2];
    const float* g1  = (const float*)d_in[3];
    const float* be1 = (const float*)d_in[4];
    const float* m1  = (const float*)d_in[5];
    const float* v1  = (const float*)d_in[6];
    const float* w2  = (const float*)d_in[7];
    const float* b2  = (const float*)d_in[8];
    const float* g2  = (const float*)d_in[9];
    const float* be2 = (const float*)d_in[10];
    const float* m2  = (const float*)d_in[11];
    const float* v2  = (const float*)d_in[12];
    const float* wv  = (const float*)d_in[13];

    float* out = (float*)d_out;
    // workspace: t4 (32 planes x 8B = 4.2 MB) | xbf (64 uint4 planes x 16B = 16.8 MB)
    ushort4* t4  = (ushort4*)d_ws;
    uint4*   xbf = (uint4*)((char*)d_ws + (size_t)32 * HW * 8);

    dim3 blk(256);
    dim3 gt(16, 2, HW / 256);      // TASK-MAJOR: id%8 == p -> XCD-local xbf
    dim3 gfd(16, 64);              // (bg, tile): id%8 == g -> XCD locality

    hipLaunchKernelGGL(la_t, gt, blk, 0, stream,
                       x, w1, b1, g1, be1, m1, v1, t4, xbf);
    hipLaunchKernelGGL(la_fused, gfd, blk, 0, stream,
                       w2, b2, g2, be2, m2, v2, wv, t4, xbf, out);
}